// Round 12
// baseline (1923.039 us; speedup 1.0000x reference)
//
#include <hip/hip_runtime.h>
#include <hip/hip_bf16.h>

#define NN 50000
#define NROWS (NN + 1)           // +1 sentinel zero row
#define NE 1600000
#define NEPAD 1951024            // >= NE + 7*NN = 1,950,000; multiple of 4
#define DIM 128
#define NG 64
#define EPSV 1e-5f
#define NCHUNK 49                // ceil(50000/1024)
#define UNROLL 8                 // table rows in flight per wave
#define NXCD 8
#define SHARD_COLS (NN / NXCD)   // 6250
#define FILL_CHUNKS 256          // edge chunks; grid = 8 * FILL_CHUNKS
#define GK 128                   // pool GEMM k-chunks
#define SCHUNK 391               // ceil(NN/GK)

typedef __attribute__((ext_vector_type(8))) __bf16 bf16x8;
typedef __attribute__((ext_vector_type(2))) __bf16 bf16x2;
typedef __attribute__((ext_vector_type(16))) float f32x16;

// ---------------- CSR build ----------------

__global__ void count_kernel(const int* __restrict__ ecol, int* __restrict__ cnt) {
    int e = blockIdx.x * 256 + threadIdx.x;
    if (e < NE) atomicAdd(&cnt[__builtin_nontemporal_load(&ecol[e])], 1);
}

// scan PADDED degrees: pdeg = ceil(cnt/8)*8 (self-loop handled separately)
__global__ void scan_chunk(const int* __restrict__ cnt, int* __restrict__ excl,
                           int* __restrict__ csum) {
    __shared__ int lds[256];
    int t = threadIdx.x;
    int base = blockIdx.x * 1024 + t * 4;
    int v0 = (base + 0 < NN) ? ((cnt[base + 0] + 7) & ~7) : 0;
    int v1 = (base + 1 < NN) ? ((cnt[base + 1] + 7) & ~7) : 0;
    int v2 = (base + 2 < NN) ? ((cnt[base + 2] + 7) & ~7) : 0;
    int v3 = (base + 3 < NN) ? ((cnt[base + 3] + 7) & ~7) : 0;
    int s = v0 + v1 + v2 + v3;
    lds[t] = s;
    __syncthreads();
    for (int off = 1; off < 256; off <<= 1) {
        int x = (t >= off) ? lds[t - off] : 0;
        __syncthreads();
        lds[t] += x;
        __syncthreads();
    }
    int run = lds[t] - s;           // exclusive prefix within chunk
    if (t == 255) csum[blockIdx.x] = lds[t];
    if (base + 0 < NN) excl[base + 0] = run; run += v0;
    if (base + 1 < NN) excl[base + 1] = run; run += v1;
    if (base + 2 < NN) excl[base + 2] = run; run += v2;
    if (base + 3 < NN) excl[base + 3] = run;
}

__global__ void scan_tail(const int* __restrict__ csum, int* __restrict__ coff,
                          int* __restrict__ row_ptr, int nch) {
    int l = threadIdx.x;
    int v = (l < nch) ? csum[l] : 0;
    int s = v;
    for (int o = 1; o < 64; o <<= 1) {
        int x = __shfl_up(s, o);
        if (l >= o) s += x;
    }
    if (l < nch) coff[l] = s - v;   // exclusive chunk offsets
    if (l == nch - 1) row_ptr[NN] = s;   // total padded edges
}

__global__ void fixup_kernel(int* __restrict__ row_ptr, const int* __restrict__ coff,
                             const int* __restrict__ cnt, float* __restrict__ dinv,
                             int* __restrict__ cursor) {
    int n = blockIdx.x * 256 + threadIdx.x;
    if (n < NN) {
        int rp = row_ptr[n] + coff[n >> 10];
        row_ptr[n] = rp;
        cursor[n] = rp;
        dinv[n] = rsqrtf((float)(cnt[n] + 1));   // +1 for self-loop
    }
}

// pre-fill padded esrc with sentinel NN (points at the zero row)
__global__ void sentinel_kernel(int4* __restrict__ esrc4) {
    const int4 v = {NN, NN, NN, NN};
    for (int i = blockIdx.x * 256 + threadIdx.x; i < NEPAD / 4; i += gridDim.x * 256)
        esrc4[i] = v;
}

// XCD-sharded scatter: block b handles col-shard (b&7) over edge-chunk (b>>3);
// each esrc/cursor line is written by exactly one XCD -> full lines in L2.
__global__ void fill_kernel(const int* __restrict__ erow, const int* __restrict__ ecol,
                            int* __restrict__ cursor, int* __restrict__ esrc) {
    const int shard = blockIdx.x & (NXCD - 1);
    const int chunk = blockIdx.x >> 3;
    const int lo = shard * SHARD_COLS;
    const int hi = lo + SHARD_COLS;       // NN divisible by 8
    for (int e = chunk * 256 + threadIdx.x; e < NE; e += FILL_CHUNKS * 256) {
        const int c = __builtin_nontemporal_load(&ecol[e]);
        if (c >= lo && c < hi) {
            int pos = atomicAdd(&cursor[c], 1);
            esrc[pos] = __builtin_nontemporal_load(&erow[e]);
        }
    }
}

// fold bias+BN into per-col scale/shift; zero the sentinel row of tbuf.
__global__ void bn_prep_kernel(const float* __restrict__ b1, const float* __restrict__ g1,
                               const float* __restrict__ be1, const float* __restrict__ rm1,
                               const float* __restrict__ rv1,
                               const float* __restrict__ b2, const float* __restrict__ g2,
                               const float* __restrict__ be2, const float* __restrict__ rm2,
                               const float* __restrict__ rv2,
                               float* __restrict__ sc1, float* __restrict__ sh1,
                               float* __restrict__ sc2, float* __restrict__ sh2,
                               __bf16* __restrict__ tbuf) {
    int c = threadIdx.x;
    if (c < DIM) {
        float s1 = g1[c] * rsqrtf(rv1[c] + EPSV);
        sc1[c] = s1;
        sh1[c] = (b1[c] - rm1[c]) * s1 + be1[c];
        float s2 = g2[c] * rsqrtf(rv2[c] + EPSV);
        sc2[c] = s2;
        sh2[c] = (b2[c] - rm2[c]) * s2 + be2[c];
        tbuf[(size_t)NN * DIM + c] = (__bf16)0.f;   // sentinel row, persists all layers
    }
}

// ---------------- dense: (h @ W) * dinv[row] -> bf16 table ----------------

__device__ __forceinline__ bf16x8 load8(const float* p) {
    float4 lo = ((const float4*)p)[0], hi = ((const float4*)p)[1];
    bf16x8 a;
    a[0] = (__bf16)lo.x; a[1] = (__bf16)lo.y; a[2] = (__bf16)lo.z; a[3] = (__bf16)lo.w;
    a[4] = (__bf16)hi.x; a[5] = (__bf16)hi.y; a[6] = (__bf16)hi.z; a[7] = (__bf16)hi.w;
    return a;
}
__device__ __forceinline__ bf16x8 load8(const __bf16* p) {
    return *(const bf16x8*)p;
}

template <typename T>
__global__ void __launch_bounds__(256) matmul_kernel(const T* __restrict__ h,
                                                     const float* __restrict__ W,
                                                     const float* __restrict__ dinv,
                                                     __bf16* __restrict__ t) {
    const int wave = threadIdx.x >> 6;
    const int lane = threadIdx.x & 63;
    const int col = wave * 32 + (lane & 31);
    const int khalf = (lane >> 5) * 8;   // 0 or 8

    bf16x8 b[8];
#pragma unroll
    for (int kc = 0; kc < 8; kc++) {
#pragma unroll
        for (int j = 0; j < 8; j++) {
            b[kc][j] = (__bf16)W[(kc * 16 + khalf + j) * DIM + col];
        }
    }

    const int ntiles = (NN + 31) / 32;
    for (int tile = blockIdx.x; tile < ntiles; tile += gridDim.x) {
        const int arow = tile * 32 + (lane & 31);
        const int arow_c = (arow < NN) ? arow : (NN - 1);  // clamped load; bad rows not stored
        f32x16 acc = {};
#pragma unroll
        for (int kc = 0; kc < 8; kc++) {
            bf16x8 a = load8(h + (size_t)arow_c * DIM + kc * 16 + khalf);
            acc = __builtin_amdgcn_mfma_f32_32x32x16_bf16(a, b[kc], acc, 0, 0, 0);
        }
#pragma unroll
        for (int r = 0; r < 16; r++) {
            int orow = tile * 32 + (r & 3) + 8 * (r >> 2) + 4 * (lane >> 5);
            if (orow < NN) t[(size_t)orow * DIM + col] = (__bf16)(acc[r] * dinv[orow]);
        }
    }
}

// ---------------- sparse: pull-gather, full-row, sentinel-padded ----------
// One wave per node; lane handles cols {2*lane, 2*lane+1}; one instruction
// reads one full 256B table row. Edge lists padded to x8 with sentinel row NN
// (zeros): wave-uniform bounds, zero predication. UNROLL=8 rows in flight.

__device__ __forceinline__ float lo16(unsigned u) { return __uint_as_float(u << 16); }
__device__ __forceinline__ float hi16(unsigned u) { return __uint_as_float(u & 0xffff0000u); }

__device__ __forceinline__ void gather_core(
    const unsigned* __restrict__ t32, const int* __restrict__ esrc,
    int beg, int end, int lane, float& ax, float& ay) {
    for (int e = beg; e < end; e += UNROLL) {    // end-beg is a multiple of 8
        int s[UNROLL];
        unsigned u[UNROLL];
#pragma unroll
        for (int i = 0; i < UNROLL; i++) s[i] = esrc[e + i];   // wave-uniform -> s_load
#pragma unroll
        for (int i = 0; i < UNROLL; i++) {
            const unsigned idx = ((unsigned)s[i] << 6) + lane;
            u[i] = __builtin_nontemporal_load(&t32[idx]);
        }
#pragma unroll
        for (int i = 0; i < UNROLL; i++) {
            ax += lo16(u[i]);
            ay += hi16(u[i]);
        }
    }
}

__global__ void __launch_bounds__(256) gather_bn_kernel(
    const unsigned* __restrict__ t32, const int* __restrict__ row_ptr,
    const int* __restrict__ esrc, const float* __restrict__ dinv,
    const float* __restrict__ scale, const float* __restrict__ shift,
    __bf16* __restrict__ out) {
    const int lane = threadIdx.x & 63;
    const int n = __builtin_amdgcn_readfirstlane(blockIdx.x * 4 + (threadIdx.x >> 6));
    if (n >= NN) return;
    float ax = 0.f, ay = 0.f;
    const int beg = row_ptr[n], end = row_ptr[n + 1];
    gather_core(t32, esrc, beg, end, lane, ax, ay);
    {   // self loop (weight 1; dinv[n] applied below)
        const unsigned u = t32[((unsigned)n << 6) + lane];
        ax += lo16(u); ay += hi16(u);
    }
    const float dv = dinv[n];
    const int c0 = lane * 2, c1 = c0 + 1;
    const float vx = fmaxf(fmaf(ax, dv * scale[c0], shift[c0]), 0.f);
    const float vy = fmaxf(fmaf(ay, dv * scale[c1], shift[c1]), 0.f);
    bf16x2 o; o[0] = (__bf16)vx; o[1] = (__bf16)vy;
    *(bf16x2*)(out + (size_t)n * DIM + c0) = o;
}

// ---------------- pool via algebraic factorization ----------------
// out[g] = sum_s T3[s] * Wsg[s][g] + b3 * cntg[g], where
// Wsg[s][g] = sum_{edges s->n, batch[n]=g} dinv[n]  (+ dinv[s] self-term).
// Replaces the 4-lines/edge gather with 1 random 4B atomic line per edge.

__global__ void __launch_bounds__(256) wscatter_kernel(
    const int* __restrict__ row_ptr, const int* __restrict__ esrc,
    const float* __restrict__ dinv, const int* __restrict__ batch,
    float* __restrict__ Wsg, int* __restrict__ cntg) {
    const int lane = threadIdx.x & 63;
    const int n = __builtin_amdgcn_readfirstlane(blockIdx.x * 4 + (threadIdx.x >> 6));
    if (n >= NN) return;
    const int g = batch[n];
    const float dv = dinv[n];
    const int beg = row_ptr[n], end = row_ptr[n + 1];   // padded; sentinels hit row NN
    for (int e = beg + lane; e < end; e += 64)
        atomicAdd(&Wsg[(size_t)(unsigned)esrc[e] * 64 + g], dv);
    if (lane == 0) {
        atomicAdd(&Wsg[(size_t)(unsigned)n * 64 + g], dv);   // self loop
        atomicAdd(&cntg[g], 1);
    }
}

// split-K dense GEMM: pout[blk] += T3[s-range]^T x Wsg[s-range].
// thread t: col c = t&127, g-range g0..g0+31 (wave-uniform -> W row via s_load).
__global__ void __launch_bounds__(256) pool_gemm_kernel(
    const __bf16* __restrict__ t3, const float* __restrict__ Wsg,
    float* __restrict__ pout) {
    const int t = threadIdx.x;
    const int c = t & 127;
    const int g0 = __builtin_amdgcn_readfirstlane((t >> 7) * 32);
    const int s0 = blockIdx.x * SCHUNK;
    const int s1 = (s0 + SCHUNK < NN) ? s0 + SCHUNK : NN;
    float acc[32] = {};
#pragma unroll 2
    for (int s = s0; s < s1; ++s) {
        const float tv = (float)t3[(size_t)s * DIM + c];
        const float* __restrict__ wrow = Wsg + (size_t)s * 64 + g0;   // uniform -> s_load
#pragma unroll
        for (int j = 0; j < 32; j++) acc[j] = fmaf(tv, wrow[j], acc[j]);
    }
    float* __restrict__ po = pout + (size_t)blockIdx.x * (NG * DIM);
#pragma unroll
    for (int j = 0; j < 32; j++) po[(g0 + j) * DIM + c] = acc[j];
}

__global__ void pool_reduce_kernel(const float* __restrict__ pout,
                                   const float* __restrict__ b3,
                                   const int* __restrict__ cntg,
                                   float* __restrict__ out) {
    const int i = blockIdx.x * 256 + threadIdx.x;   // i = g*128 + c
    const int g = i >> 7, c = i & 127;
    float s = 0.f;
    for (int b = 0; b < GK; b++) s += pout[(size_t)b * (NG * DIM) + i];
    out[i] = s + b3[c] * (float)cntg[g];
}

// ---------------- launch ----------------

extern "C" void kernel_launch(void* const* d_in, const int* in_sizes, int n_in,
                              void* d_out, int out_size, void* d_ws, size_t ws_size,
                              hipStream_t stream) {
    const float* x    = (const float*)d_in[0];
    const int*   ei   = (const int*)d_in[1];
    const int*   batch= (const int*)d_in[2];
    const float* W1 = (const float*)d_in[3];
    const float* b1 = (const float*)d_in[4];
    const float* W2 = (const float*)d_in[5];
    const float* b2 = (const float*)d_in[6];
    const float* W3 = (const float*)d_in[7];
    const float* b3 = (const float*)d_in[8];
    const float* g1 = (const float*)d_in[9];
    const float* be1= (const float*)d_in[10];
    const float* rm1= (const float*)d_in[11];
    const float* rv1= (const float*)d_in[12];
    const float* g2 = (const float*)d_in[13];
    const float* be2= (const float*)d_in[14];
    const float* rm2= (const float*)d_in[15];
    const float* rv2= (const float*)d_in[16];
    const int* erow = ei;
    const int* ecol = ei + NE;

    char* ws = (char*)d_ws;
    size_t off = 0;
    auto alloc = [&](size_t bytes) -> void* {
        void* p = ws + off;
        off = (off + bytes + 255) & ~(size_t)255;
        return p;
    };
    int*    cnt     = (int*)alloc(NN * sizeof(int));
    int*    row_ptr = (int*)alloc((NN + 1) * sizeof(int));
    int*    cursor  = (int*)alloc(NN * sizeof(int));
    int*    csum    = (int*)alloc(64 * sizeof(int));
    int*    coff    = (int*)alloc(64 * sizeof(int));
    float*  dinv    = (float*)alloc(NN * sizeof(float));
    int*    cntg    = (int*)alloc(64 * sizeof(int));
    int*    esrc    = (int*)alloc(NEPAD * sizeof(int));
    __bf16* tbuf    = (__bf16*)alloc((size_t)NROWS * DIM * sizeof(__bf16));
    __bf16* hbuf    = (__bf16*)alloc((size_t)NN * DIM * sizeof(__bf16));
    float*  Wsg     = (float*)alloc((size_t)NROWS * 64 * sizeof(float));
    float*  sc1     = (float*)alloc(DIM * sizeof(float));
    float*  sh1     = (float*)alloc(DIM * sizeof(float));
    float*  sc2     = (float*)alloc(DIM * sizeof(float));
    float*  sh2     = (float*)alloc(DIM * sizeof(float));
    float*  pout    = (float*)hbuf;   // overlay: hbuf dead after matmul3 reads it

    hipMemsetAsync(cnt, 0, NN * sizeof(int), stream);
    hipMemsetAsync(cntg, 0, 64 * sizeof(int), stream);
    hipMemsetAsync(Wsg, 0, (size_t)NROWS * 64 * sizeof(float), stream);

    bn_prep_kernel<<<1, 128, 0, stream>>>(b1, g1, be1, rm1, rv1,
                                          b2, g2, be2, rm2, rv2,
                                          sc1, sh1, sc2, sh2, tbuf);
    sentinel_kernel<<<1024, 256, 0, stream>>>((int4*)esrc);
    count_kernel<<<(NE + 255) / 256, 256, 0, stream>>>(ecol, cnt);
    scan_chunk<<<NCHUNK, 256, 0, stream>>>(cnt, row_ptr, csum);
    scan_tail<<<1, 64, 0, stream>>>(csum, coff, row_ptr, NCHUNK);
    fixup_kernel<<<(NN + 255) / 256, 256, 0, stream>>>(row_ptr, coff, cnt, dinv, cursor);
    fill_kernel<<<NXCD * FILL_CHUNKS, 256, 0, stream>>>(erow, ecol, cursor, esrc);

    const unsigned* t32 = (const unsigned*)tbuf;
    const int nblk = (NN + 3) / 4;

    wscatter_kernel<<<nblk, 256, 0, stream>>>(row_ptr, esrc, dinv, batch, Wsg, cntg);

    matmul_kernel<float><<<512, 256, 0, stream>>>(x, W1, dinv, tbuf);
    gather_bn_kernel<<<nblk, 256, 0, stream>>>(t32, row_ptr, esrc, dinv,
                                               sc1, sh1, hbuf);
    matmul_kernel<__bf16><<<512, 256, 0, stream>>>(hbuf, W2, dinv, tbuf);
    gather_bn_kernel<<<nblk, 256, 0, stream>>>(t32, row_ptr, esrc, dinv,
                                               sc2, sh2, hbuf);
    matmul_kernel<__bf16><<<512, 256, 0, stream>>>(hbuf, W3, dinv, tbuf);

    pool_gemm_kernel<<<GK, 256, 0, stream>>>(tbuf, Wsg, pout);
    pool_reduce_kernel<<<(NG * DIM) / 256, 256, 0, stream>>>(pout, b3, cntg,
                                                             (float*)d_out);
}

// Round 13
// 1050.327 us; speedup vs baseline: 1.8309x; 1.8309x over previous
//
#include <hip/hip_runtime.h>
#include <hip/hip_bf16.h>

#define NN 50000
#define NROWS (NN + 1)           // +1 sentinel zero row
#define NE 1600000
#define NEPAD 1951024            // >= NE + 7*NN = 1,950,000; multiple of 4
#define DIM 128
#define NG 64
#define EPSV 1e-5f
#define NCHUNK 49                // ceil(50000/1024)
#define UNROLL 8                 // table rows in flight per wave
#define NXCD 8
#define SHARD_COLS (NN / NXCD)   // 6250
#define FILL_CHUNKS 256          // edge chunks; grid = 8 * FILL_CHUNKS
#define RS 50048                 // Wsg row stride (floats), 64B-aligned
#define KCH 8                    // pool GEMM split-K chunks
#define KS (NN / KCH)            // 6250

typedef __attribute__((ext_vector_type(8))) __bf16 bf16x8;
typedef __attribute__((ext_vector_type(2))) __bf16 bf16x2;
typedef __attribute__((ext_vector_type(16))) float f32x16;

// ---------------- CSR build ----------------

__global__ void count_kernel(const int* __restrict__ ecol, int* __restrict__ cnt) {
    int e = blockIdx.x * 256 + threadIdx.x;
    if (e < NE) atomicAdd(&cnt[ecol[e]], 1);
}

// scan PADDED degrees: pdeg = ceil(cnt/8)*8 (self-loop handled separately)
__global__ void scan_chunk(const int* __restrict__ cnt, int* __restrict__ excl,
                           int* __restrict__ csum) {
    __shared__ int lds[256];
    int t = threadIdx.x;
    int base = blockIdx.x * 1024 + t * 4;
    int v0 = (base + 0 < NN) ? ((cnt[base + 0] + 7) & ~7) : 0;
    int v1 = (base + 1 < NN) ? ((cnt[base + 1] + 7) & ~7) : 0;
    int v2 = (base + 2 < NN) ? ((cnt[base + 2] + 7) & ~7) : 0;
    int v3 = (base + 3 < NN) ? ((cnt[base + 3] + 7) & ~7) : 0;
    int s = v0 + v1 + v2 + v3;
    lds[t] = s;
    __syncthreads();
    for (int off = 1; off < 256; off <<= 1) {
        int x = (t >= off) ? lds[t - off] : 0;
        __syncthreads();
        lds[t] += x;
        __syncthreads();
    }
    int run = lds[t] - s;           // exclusive prefix within chunk
    if (t == 255) csum[blockIdx.x] = lds[t];
    if (base + 0 < NN) excl[base + 0] = run; run += v0;
    if (base + 1 < NN) excl[base + 1] = run; run += v1;
    if (base + 2 < NN) excl[base + 2] = run; run += v2;
    if (base + 3 < NN) excl[base + 3] = run;
}

__global__ void scan_tail(const int* __restrict__ csum, int* __restrict__ coff,
                          int* __restrict__ row_ptr, int nch) {
    int l = threadIdx.x;
    int v = (l < nch) ? csum[l] : 0;
    int s = v;
    for (int o = 1; o < 64; o <<= 1) {
        int x = __shfl_up(s, o);
        if (l >= o) s += x;
    }
    if (l < nch) coff[l] = s - v;   // exclusive chunk offsets
    if (l == nch - 1) row_ptr[NN] = s;   // total padded edges
}

__global__ void fixup_kernel(int* __restrict__ row_ptr, const int* __restrict__ coff,
                             const int* __restrict__ cnt, const int* __restrict__ batch,
                             float* __restrict__ dinv, int* __restrict__ cursor,
                             int* __restrict__ cntg) {
    int n = blockIdx.x * 256 + threadIdx.x;
    if (n < NN) {
        int rp = row_ptr[n] + coff[n >> 10];
        row_ptr[n] = rp;
        cursor[n] = rp;
        dinv[n] = rsqrtf((float)(cnt[n] + 1));   // +1 for self-loop
        atomicAdd(&cntg[batch[n]], 1);
    }
}

// pre-fill padded esrc with sentinel NN (points at the zero row)
__global__ void sentinel_kernel(int4* __restrict__ esrc4) {
    const int4 v = {NN, NN, NN, NN};
    for (int i = blockIdx.x * 256 + threadIdx.x; i < NEPAD / 4; i += gridDim.x * 256)
        esrc4[i] = v;
}

// XCD-sharded scatter: block b handles col-shard (b&7) over edge-chunk (b>>3);
// each esrc/cursor line is written by exactly one XCD -> full lines in L2.
// Plain (cacheable) loads: L3 serves the 8x ecol re-read.
__global__ void fill_kernel(const int* __restrict__ erow, const int* __restrict__ ecol,
                            int* __restrict__ cursor, int* __restrict__ esrc) {
    const int shard = blockIdx.x & (NXCD - 1);
    const int chunk = blockIdx.x >> 3;
    const int lo = shard * SHARD_COLS;
    const int hi = lo + SHARD_COLS;       // NN divisible by 8
    for (int e = chunk * 256 + threadIdx.x; e < NE; e += FILL_CHUNKS * 256) {
        const int c = ecol[e];
        if (c >= lo && c < hi) {
            int pos = atomicAdd(&cursor[c], 1);
            esrc[pos] = erow[e];
        }
    }
}

// fold bias+BN into per-col scale/shift; zero the sentinel row of tbuf.
__global__ void bn_prep_kernel(const float* __restrict__ b1, const float* __restrict__ g1,
                               const float* __restrict__ be1, const float* __restrict__ rm1,
                               const float* __restrict__ rv1,
                               const float* __restrict__ b2, const float* __restrict__ g2,
                               const float* __restrict__ be2, const float* __restrict__ rm2,
                               const float* __restrict__ rv2,
                               float* __restrict__ sc1, float* __restrict__ sh1,
                               float* __restrict__ sc2, float* __restrict__ sh2,
                               __bf16* __restrict__ tbuf) {
    int c = threadIdx.x;
    if (c < DIM) {
        float s1 = g1[c] * rsqrtf(rv1[c] + EPSV);
        sc1[c] = s1;
        sh1[c] = (b1[c] - rm1[c]) * s1 + be1[c];
        float s2 = g2[c] * rsqrtf(rv2[c] + EPSV);
        sc2[c] = s2;
        sh2[c] = (b2[c] - rm2[c]) * s2 + be2[c];
        tbuf[(size_t)NN * DIM + c] = (__bf16)0.f;   // sentinel row, persists all layers
    }
}

// ---------------- dense: (h @ W) * dinv[row] -> bf16 table ----------------

__device__ __forceinline__ bf16x8 load8(const float* p) {
    float4 lo = ((const float4*)p)[0], hi = ((const float4*)p)[1];
    bf16x8 a;
    a[0] = (__bf16)lo.x; a[1] = (__bf16)lo.y; a[2] = (__bf16)lo.z; a[3] = (__bf16)lo.w;
    a[4] = (__bf16)hi.x; a[5] = (__bf16)hi.y; a[6] = (__bf16)hi.z; a[7] = (__bf16)hi.w;
    return a;
}
__device__ __forceinline__ bf16x8 load8(const __bf16* p) {
    return *(const bf16x8*)p;
}

template <typename T>
__global__ void __launch_bounds__(256) matmul_kernel(const T* __restrict__ h,
                                                     const float* __restrict__ W,
                                                     const float* __restrict__ dinv,
                                                     __bf16* __restrict__ t) {
    const int wave = threadIdx.x >> 6;
    const int lane = threadIdx.x & 63;
    const int col = wave * 32 + (lane & 31);
    const int khalf = (lane >> 5) * 8;   // 0 or 8

    bf16x8 b[8];
#pragma unroll
    for (int kc = 0; kc < 8; kc++) {
#pragma unroll
        for (int j = 0; j < 8; j++) {
            b[kc][j] = (__bf16)W[(kc * 16 + khalf + j) * DIM + col];
        }
    }

    const int ntiles = (NN + 31) / 32;
    for (int tile = blockIdx.x; tile < ntiles; tile += gridDim.x) {
        const int arow = tile * 32 + (lane & 31);
        const int arow_c = (arow < NN) ? arow : (NN - 1);  // clamped load; bad rows not stored
        f32x16 acc = {};
#pragma unroll
        for (int kc = 0; kc < 8; kc++) {
            bf16x8 a = load8(h + (size_t)arow_c * DIM + kc * 16 + khalf);
            acc = __builtin_amdgcn_mfma_f32_32x32x16_bf16(a, b[kc], acc, 0, 0, 0);
        }
#pragma unroll
        for (int r = 0; r < 16; r++) {
            int orow = tile * 32 + (r & 3) + 8 * (r >> 2) + 4 * (lane >> 5);
            if (orow < NN) t[(size_t)orow * DIM + col] = (__bf16)(acc[r] * dinv[orow]);
        }
    }
}

// ---------------- sparse: pull-gather, full-row, sentinel-padded ----------
// One wave per node; lane handles cols {2*lane, 2*lane+1}; one instruction
// reads one full 256B table row. Edge lists padded to x8 with sentinel row NN
// (zeros): wave-uniform bounds, zero predication. UNROLL=8 rows in flight.

__device__ __forceinline__ float lo16(unsigned u) { return __uint_as_float(u << 16); }
__device__ __forceinline__ float hi16(unsigned u) { return __uint_as_float(u & 0xffff0000u); }

__device__ __forceinline__ void gather_core(
    const unsigned* __restrict__ t32, const int* __restrict__ esrc,
    int beg, int end, int lane, float& ax, float& ay) {
    for (int e = beg; e < end; e += UNROLL) {    // end-beg is a multiple of 8
        int s[UNROLL];
        unsigned u[UNROLL];
#pragma unroll
        for (int i = 0; i < UNROLL; i++) s[i] = esrc[e + i];   // wave-uniform -> s_load
#pragma unroll
        for (int i = 0; i < UNROLL; i++) {
            const unsigned idx = ((unsigned)s[i] << 6) + lane;
            u[i] = t32[idx];
        }
#pragma unroll
        for (int i = 0; i < UNROLL; i++) {
            ax += lo16(u[i]);
            ay += hi16(u[i]);
        }
    }
}

__global__ void __launch_bounds__(256) gather_bn_kernel(
    const unsigned* __restrict__ t32, const int* __restrict__ row_ptr,
    const int* __restrict__ esrc, const float* __restrict__ dinv,
    const float* __restrict__ scale, const float* __restrict__ shift,
    __bf16* __restrict__ out) {
    const int lane = threadIdx.x & 63;
    const int n = __builtin_amdgcn_readfirstlane(blockIdx.x * 4 + (threadIdx.x >> 6));
    if (n >= NN) return;
    float ax = 0.f, ay = 0.f;
    const int beg = row_ptr[n], end = row_ptr[n + 1];
    gather_core(t32, esrc, beg, end, lane, ax, ay);
    {   // self loop (weight 1; dinv[n] applied below)
        const unsigned u = t32[((unsigned)n << 6) + lane];
        ax += lo16(u); ay += hi16(u);
    }
    const float dv = dinv[n];
    const int c0 = lane * 2, c1 = c0 + 1;
    const float vx = fmaxf(fmaf(ax, dv * scale[c0], shift[c0]), 0.f);
    const float vy = fmaxf(fmaf(ay, dv * scale[c1], shift[c1]), 0.f);
    bf16x2 o; o[0] = (__bf16)vx; o[1] = (__bf16)vy;
    *(bf16x2*)(out + (size_t)n * DIM + c0) = o;
}

// ---------------- pool via algebraic factorization ----------------
// out[g] = sum_s T3[s] * Wsg[g][s] + b3 * cntg[g], where
// Wsg[g][s] = sum_{edges s->n, batch[n]=g} dinv[n] (+ dinv[n] self-term at s=n).
// Build in CSR (sorted-batch) order: at any instant only ~2 graph rows
// (2 x 200KB, ~6K lines) receive atomics -> count_kernel's fast regime,
// unlike r12's 1.95M unique cold lines.

__global__ void __launch_bounds__(256) wscatter_kernel(
    const int* __restrict__ row_ptr, const int* __restrict__ esrc,
    const float* __restrict__ dinv, const int* __restrict__ batch,
    float* __restrict__ Wsg) {
    const int lane = threadIdx.x & 63;
    const int n = __builtin_amdgcn_readfirstlane(blockIdx.x * 4 + (threadIdx.x >> 6));
    if (n >= NN) return;
    const int g = batch[n];
    const float dv = dinv[n];
    float* __restrict__ wrow = Wsg + (size_t)g * RS;
    const int beg = row_ptr[n], end = row_ptr[n + 1];   // padded bounds
    for (int e = beg + lane; e < end; e += 64) {
        const int s = esrc[e];
        if (s != NN) atomicAdd(&wrow[s], dv);           // skip sentinel slots
    }
    if (lane == 0) atomicAdd(&wrow[n], dv);             // self loop
}

// split-K GEMM: pout[g][k] = sum_{s in chunk k} T3[s][:] * Wsg[g][s].
// W chunk is wave-uniform (s_load); T3 row read coalesced (128 x bf16).
__global__ void __launch_bounds__(128) pool_gemm_kernel(
    const __bf16* __restrict__ t3, const float* __restrict__ Wsg,
    float* __restrict__ pout) {
    const int c = threadIdx.x;           // 0..127
    const int g = blockIdx.x & 63;
    const int k = blockIdx.x >> 6;       // 0..KCH-1
    const float* __restrict__ wrow = Wsg + (size_t)g * RS + k * KS;
    const __bf16* __restrict__ tp = t3 + (size_t)k * KS * DIM + c;
    float acc = 0.f;
#pragma unroll 8
    for (int s = 0; s < KS; ++s)
        acc = fmaf((float)tp[(size_t)s * DIM], wrow[s], acc);
    pout[((size_t)g * KCH + k) * DIM + c] = acc;
}

__global__ void pool_reduce_kernel(const float* __restrict__ pout,
                                   const float* __restrict__ b3,
                                   const int* __restrict__ cntg,
                                   float* __restrict__ out) {
    const int i = blockIdx.x * 256 + threadIdx.x;   // i = g*128 + c
    const int g = i >> 7, c = i & 127;
    float s = 0.f;
#pragma unroll
    for (int k = 0; k < KCH; k++) s += pout[((size_t)g * KCH + k) * DIM + c];
    out[i] = s + b3[c] * (float)cntg[g];
}

// ---------------- launch ----------------

extern "C" void kernel_launch(void* const* d_in, const int* in_sizes, int n_in,
                              void* d_out, int out_size, void* d_ws, size_t ws_size,
                              hipStream_t stream) {
    const float* x    = (const float*)d_in[0];
    const int*   ei   = (const int*)d_in[1];
    const int*   batch= (const int*)d_in[2];
    const float* W1 = (const float*)d_in[3];
    const float* b1 = (const float*)d_in[4];
    const float* W2 = (const float*)d_in[5];
    const float* b2 = (const float*)d_in[6];
    const float* W3 = (const float*)d_in[7];
    const float* b3 = (const float*)d_in[8];
    const float* g1 = (const float*)d_in[9];
    const float* be1= (const float*)d_in[10];
    const float* rm1= (const float*)d_in[11];
    const float* rv1= (const float*)d_in[12];
    const float* g2 = (const float*)d_in[13];
    const float* be2= (const float*)d_in[14];
    const float* rm2= (const float*)d_in[15];
    const float* rv2= (const float*)d_in[16];
    const int* erow = ei;
    const int* ecol = ei + NE;

    char* ws = (char*)d_ws;
    size_t off = 0;
    auto alloc = [&](size_t bytes) -> void* {
        void* p = ws + off;
        off = (off + bytes + 255) & ~(size_t)255;
        return p;
    };
    int*    cnt     = (int*)alloc(NN * sizeof(int));
    int*    row_ptr = (int*)alloc((NN + 1) * sizeof(int));
    int*    cursor  = (int*)alloc(NN * sizeof(int));
    int*    csum    = (int*)alloc(64 * sizeof(int));
    int*    coff    = (int*)alloc(64 * sizeof(int));
    float*  dinv    = (float*)alloc(NN * sizeof(float));
    int*    cntg    = (int*)alloc(64 * sizeof(int));
    int*    esrc    = (int*)alloc(NEPAD * sizeof(int));
    __bf16* tbuf    = (__bf16*)alloc((size_t)NROWS * DIM * sizeof(__bf16));
    __bf16* hbuf    = (__bf16*)alloc((size_t)NN * DIM * sizeof(__bf16));
    float*  Wsg     = (float*)alloc((size_t)NG * RS * sizeof(float));
    float*  sc1     = (float*)alloc(DIM * sizeof(float));
    float*  sh1     = (float*)alloc(DIM * sizeof(float));
    float*  sc2     = (float*)alloc(DIM * sizeof(float));
    float*  sh2     = (float*)alloc(DIM * sizeof(float));
    float*  pout    = (float*)hbuf;   // overlay: hbuf dead after matmul3 reads it

    hipMemsetAsync(cnt, 0, NN * sizeof(int), stream);
    hipMemsetAsync(cntg, 0, 64 * sizeof(int), stream);
    hipMemsetAsync(Wsg, 0, (size_t)NG * RS * sizeof(float), stream);

    bn_prep_kernel<<<1, 128, 0, stream>>>(b1, g1, be1, rm1, rv1,
                                          b2, g2, be2, rm2, rv2,
                                          sc1, sh1, sc2, sh2, tbuf);
    sentinel_kernel<<<1024, 256, 0, stream>>>((int4*)esrc);
    count_kernel<<<(NE + 255) / 256, 256, 0, stream>>>(ecol, cnt);
    scan_chunk<<<NCHUNK, 256, 0, stream>>>(cnt, row_ptr, csum);
    scan_tail<<<1, 64, 0, stream>>>(csum, coff, row_ptr, NCHUNK);
    fixup_kernel<<<(NN + 255) / 256, 256, 0, stream>>>(row_ptr, coff, cnt, batch,
                                                       dinv, cursor, cntg);
    fill_kernel<<<NXCD * FILL_CHUNKS, 256, 0, stream>>>(erow, ecol, cursor, esrc);

    const unsigned* t32 = (const unsigned*)tbuf;
    const int nblk = (NN + 3) / 4;

    wscatter_kernel<<<nblk, 256, 0, stream>>>(row_ptr, esrc, dinv, batch, Wsg);

    matmul_kernel<float><<<512, 256, 0, stream>>>(x, W1, dinv, tbuf);
    gather_bn_kernel<<<nblk, 256, 0, stream>>>(t32, row_ptr, esrc, dinv,
                                               sc1, sh1, hbuf);
    matmul_kernel<__bf16><<<512, 256, 0, stream>>>(hbuf, W2, dinv, tbuf);
    gather_bn_kernel<<<nblk, 256, 0, stream>>>(t32, row_ptr, esrc, dinv,
                                               sc2, sh2, hbuf);
    matmul_kernel<__bf16><<<512, 256, 0, stream>>>(hbuf, W3, dinv, tbuf);

    pool_gemm_kernel<<<NG * KCH, 128, 0, stream>>>(tbuf, Wsg, pout);
    pool_reduce_kernel<<<(NG * DIM) / 256, 256, 0, stream>>>(pout, b3, cntg,
                                                             (float*)d_out);
}

// Round 14
// 385.456 us; speedup vs baseline: 4.9890x; 2.7249x over previous
//
#include <hip/hip_runtime.h>
#include <hip/hip_bf16.h>

#define NN 50000
#define NROWS (NN + 1)           // +1 sentinel zero row
#define NE 1600000
#define NEPAD 1951024            // >= NE + 7*NN = 1,950,000; multiple of 4
#define DIM 128
#define NG 64
#define EPSV 1e-5f
#define NCHUNK 49                // ceil(50000/1024)
#define UNROLL 8                 // table rows in flight per wave
#define RUN 4                    // nodes per wave in pool kernel
#define NXCD 8
#define SHARD_COLS (NN / NXCD)   // 6250
#define FILL_CHUNKS 256          // edge chunks; grid = 8 * FILL_CHUNKS

typedef __attribute__((ext_vector_type(8))) __bf16 bf16x8;
typedef __attribute__((ext_vector_type(2))) __bf16 bf16x2;
typedef __attribute__((ext_vector_type(16))) float f32x16;

// ---------------- CSR build ----------------

__global__ void count_kernel(const int4* __restrict__ ecol4, int* __restrict__ cnt) {
    int i = blockIdx.x * 256 + threadIdx.x;
    if (i < NE / 4) {
        int4 c = ecol4[i];
        atomicAdd(&cnt[c.x], 1);
        atomicAdd(&cnt[c.y], 1);
        atomicAdd(&cnt[c.z], 1);
        atomicAdd(&cnt[c.w], 1);
    }
}

// scan PADDED degrees: pdeg = ceil(cnt/8)*8 (self-loop handled separately)
__global__ void scan_chunk(const int* __restrict__ cnt, int* __restrict__ excl,
                           int* __restrict__ csum) {
    __shared__ int lds[256];
    int t = threadIdx.x;
    int base = blockIdx.x * 1024 + t * 4;
    int v0 = (base + 0 < NN) ? ((cnt[base + 0] + 7) & ~7) : 0;
    int v1 = (base + 1 < NN) ? ((cnt[base + 1] + 7) & ~7) : 0;
    int v2 = (base + 2 < NN) ? ((cnt[base + 2] + 7) & ~7) : 0;
    int v3 = (base + 3 < NN) ? ((cnt[base + 3] + 7) & ~7) : 0;
    int s = v0 + v1 + v2 + v3;
    lds[t] = s;
    __syncthreads();
    for (int off = 1; off < 256; off <<= 1) {
        int x = (t >= off) ? lds[t - off] : 0;
        __syncthreads();
        lds[t] += x;
        __syncthreads();
    }
    int run = lds[t] - s;           // exclusive prefix within chunk
    if (t == 255) csum[blockIdx.x] = lds[t];
    if (base + 0 < NN) excl[base + 0] = run; run += v0;
    if (base + 1 < NN) excl[base + 1] = run; run += v1;
    if (base + 2 < NN) excl[base + 2] = run; run += v2;
    if (base + 3 < NN) excl[base + 3] = run;
}

__global__ void scan_tail(const int* __restrict__ csum, int* __restrict__ coff,
                          int* __restrict__ row_ptr, int nch) {
    int l = threadIdx.x;
    int v = (l < nch) ? csum[l] : 0;
    int s = v;
    for (int o = 1; o < 64; o <<= 1) {
        int x = __shfl_up(s, o);
        if (l >= o) s += x;
    }
    if (l < nch) coff[l] = s - v;   // exclusive chunk offsets
    if (l == nch - 1) row_ptr[NN] = s;   // total padded edges
}

__global__ void fixup_kernel(int* __restrict__ row_ptr, const int* __restrict__ coff,
                             const int* __restrict__ cnt, float* __restrict__ dinv,
                             int* __restrict__ cursor) {
    int n = blockIdx.x * 256 + threadIdx.x;
    if (n < NN) {
        int rp = row_ptr[n] + coff[n >> 10];
        row_ptr[n] = rp;
        cursor[n] = rp;
        dinv[n] = rsqrtf((float)(cnt[n] + 1));   // +1 for self-loop
    }
}

// pre-fill padded esrc with sentinel NN (points at the zero row)
__global__ void sentinel_kernel(int4* __restrict__ esrc4) {
    const int4 v = {NN, NN, NN, NN};
    for (int i = blockIdx.x * 256 + threadIdx.x; i < NEPAD / 4; i += gridDim.x * 256)
        esrc4[i] = v;
}

// XCD-sharded scatter: block b handles col-shard (b&7) over edge-chunk (b>>3);
// each esrc/cursor line is written by exactly one XCD -> full lines in L2.
// Plain (cacheable) loads: L3 serves the 8x ecol re-read.
__global__ void fill_kernel(const int* __restrict__ erow, const int* __restrict__ ecol,
                            int* __restrict__ cursor, int* __restrict__ esrc) {
    const int shard = blockIdx.x & (NXCD - 1);
    const int chunk = blockIdx.x >> 3;
    const int lo = shard * SHARD_COLS;
    const int hi = lo + SHARD_COLS;       // NN divisible by 8
    for (int e = chunk * 256 + threadIdx.x; e < NE; e += FILL_CHUNKS * 256) {
        const int c = ecol[e];
        if (c >= lo && c < hi) {
            int pos = atomicAdd(&cursor[c], 1);
            esrc[pos] = erow[e];
        }
    }
}

// fold bias+BN into per-col scale/shift; zero the sentinel row of tbuf.
__global__ void bn_prep_kernel(const float* __restrict__ b1, const float* __restrict__ g1,
                               const float* __restrict__ be1, const float* __restrict__ rm1,
                               const float* __restrict__ rv1,
                               const float* __restrict__ b2, const float* __restrict__ g2,
                               const float* __restrict__ be2, const float* __restrict__ rm2,
                               const float* __restrict__ rv2,
                               float* __restrict__ sc1, float* __restrict__ sh1,
                               float* __restrict__ sc2, float* __restrict__ sh2,
                               __bf16* __restrict__ tbuf) {
    int c = threadIdx.x;
    if (c < DIM) {
        float s1 = g1[c] * rsqrtf(rv1[c] + EPSV);
        sc1[c] = s1;
        sh1[c] = (b1[c] - rm1[c]) * s1 + be1[c];
        float s2 = g2[c] * rsqrtf(rv2[c] + EPSV);
        sc2[c] = s2;
        sh2[c] = (b2[c] - rm2[c]) * s2 + be2[c];
        tbuf[(size_t)NN * DIM + c] = (__bf16)0.f;   // sentinel row, persists all layers
    }
}

// ---------------- dense: (h @ W) * dinv[row] -> bf16 table ----------------

__device__ __forceinline__ bf16x8 load8(const float* p) {
    float4 lo = ((const float4*)p)[0], hi = ((const float4*)p)[1];
    bf16x8 a;
    a[0] = (__bf16)lo.x; a[1] = (__bf16)lo.y; a[2] = (__bf16)lo.z; a[3] = (__bf16)lo.w;
    a[4] = (__bf16)hi.x; a[5] = (__bf16)hi.y; a[6] = (__bf16)hi.z; a[7] = (__bf16)hi.w;
    return a;
}
__device__ __forceinline__ bf16x8 load8(const __bf16* p) {
    return *(const bf16x8*)p;
}

template <typename T>
__global__ void __launch_bounds__(256) matmul_kernel(const T* __restrict__ h,
                                                     const float* __restrict__ W,
                                                     const float* __restrict__ dinv,
                                                     __bf16* __restrict__ t) {
    const int wave = threadIdx.x >> 6;
    const int lane = threadIdx.x & 63;
    const int col = wave * 32 + (lane & 31);
    const int khalf = (lane >> 5) * 8;   // 0 or 8

    bf16x8 b[8];
#pragma unroll
    for (int kc = 0; kc < 8; kc++) {
#pragma unroll
        for (int j = 0; j < 8; j++) {
            b[kc][j] = (__bf16)W[(kc * 16 + khalf + j) * DIM + col];
        }
    }

    const int ntiles = (NN + 31) / 32;
    for (int tile = blockIdx.x; tile < ntiles; tile += gridDim.x) {
        const int arow = tile * 32 + (lane & 31);
        const int arow_c = (arow < NN) ? arow : (NN - 1);  // clamped load; bad rows not stored
        f32x16 acc = {};
#pragma unroll
        for (int kc = 0; kc < 8; kc++) {
            bf16x8 a = load8(h + (size_t)arow_c * DIM + kc * 16 + khalf);
            acc = __builtin_amdgcn_mfma_f32_32x32x16_bf16(a, b[kc], acc, 0, 0, 0);
        }
#pragma unroll
        for (int r = 0; r < 16; r++) {
            int orow = tile * 32 + (r & 3) + 8 * (r >> 2) + 4 * (lane >> 5);
            if (orow < NN) t[(size_t)orow * DIM + col] = (__bf16)(acc[r] * dinv[orow]);
        }
    }
}

// ---------------- sparse: pull-gather, full-row, sentinel-padded ----------
// One wave per node; lane handles cols {2*lane, 2*lane+1}; one instruction
// reads one full 256B table row (best TA shape: 1 segment, 4 lines). Edge
// lists padded to x8 with sentinel row NN (zeros): wave-uniform bounds, zero
// predication. UNROLL=8 rows in flight. PLAIN cacheable loads so the 12.8MB
// table is L3-resident across its 3x re-read -> lower miss latency.

__device__ __forceinline__ float lo16(unsigned u) { return __uint_as_float(u << 16); }
__device__ __forceinline__ float hi16(unsigned u) { return __uint_as_float(u & 0xffff0000u); }

__device__ __forceinline__ void gather_core(
    const unsigned* __restrict__ t32, const int* __restrict__ esrc,
    int beg, int end, int lane, float& ax, float& ay) {
    for (int e = beg; e < end; e += UNROLL) {    // end-beg is a multiple of 8
        int s[UNROLL];
        unsigned u[UNROLL];
#pragma unroll
        for (int i = 0; i < UNROLL; i++) s[i] = esrc[e + i];   // wave-uniform -> s_load
#pragma unroll
        for (int i = 0; i < UNROLL; i++) {
            const unsigned idx = ((unsigned)s[i] << 6) + lane;
            u[i] = t32[idx];
        }
#pragma unroll
        for (int i = 0; i < UNROLL; i++) {
            ax += lo16(u[i]);
            ay += hi16(u[i]);
        }
    }
}

__global__ void __launch_bounds__(256) gather_bn_kernel(
    const unsigned* __restrict__ t32, const int* __restrict__ row_ptr,
    const int* __restrict__ esrc, const float* __restrict__ dinv,
    const float* __restrict__ scale, const float* __restrict__ shift,
    __bf16* __restrict__ out) {
    const int lane = threadIdx.x & 63;
    const int n = __builtin_amdgcn_readfirstlane(blockIdx.x * 4 + (threadIdx.x >> 6));
    if (n >= NN) return;
    float ax = 0.f, ay = 0.f;
    const int beg = row_ptr[n], end = row_ptr[n + 1];
    gather_core(t32, esrc, beg, end, lane, ax, ay);
    {   // self loop (weight 1; dinv[n] applied below)
        const unsigned u = t32[((unsigned)n << 6) + lane];
        ax += lo16(u); ay += hi16(u);
    }
    const float dv = dinv[n];
    const int c0 = lane * 2, c1 = c0 + 1;
    const float vx = fmaxf(fmaf(ax, dv * scale[c0], shift[c0]), 0.f);
    const float vy = fmaxf(fmaf(ay, dv * scale[c1], shift[c1]), 0.f);
    bf16x2 o; o[0] = (__bf16)vx; o[1] = (__bf16)vy;
    *(bf16x2*)(out + (size_t)n * DIM + c0) = o;
}

// Pool: batch is SORTED -> segment reduction over RUN nodes per wave; flush
// atomics only at graph boundary / run end.

__global__ void __launch_bounds__(256) gather_pool_kernel(
    const unsigned* __restrict__ t32, const int* __restrict__ row_ptr,
    const int* __restrict__ esrc, const float* __restrict__ dinv,
    const float* __restrict__ bias, const int* __restrict__ batch,
    float* __restrict__ out) {
    const int lane = threadIdx.x & 63;
    const int wid = __builtin_amdgcn_readfirstlane(blockIdx.x * 4 + (threadIdx.x >> 6));
    const int n0 = wid * RUN;            // NN % RUN == 0
    if (n0 >= NN) return;
    const int c0 = lane * 2, c1 = c0 + 1;
    const float bx = bias[c0], by = bias[c1];
    float rx = 0.f, ry = 0.f;
    int g = batch[n0];
    for (int j = 0; j < RUN; j++) {
        const int n = n0 + j;
        float ax = 0.f, ay = 0.f;
        const int beg = row_ptr[n], end = row_ptr[n + 1];
        gather_core(t32, esrc, beg, end, lane, ax, ay);
        {
            const unsigned u = t32[((unsigned)n << 6) + lane];
            ax += lo16(u); ay += hi16(u);
        }
        const float dv = dinv[n];
        const int gn = batch[n];
        if (gn != g) {   // graph boundary: flush previous segment (uniform branch)
            atomicAdd(out + (size_t)g * DIM + c0, rx);
            atomicAdd(out + (size_t)g * DIM + c1, ry);
            rx = 0.f; ry = 0.f; g = gn;
        }
        rx += fmaf(ax, dv, bx);
        ry += fmaf(ay, dv, by);
    }
    atomicAdd(out + (size_t)g * DIM + c0, rx);
    atomicAdd(out + (size_t)g * DIM + c1, ry);
}

// ---------------- launch ----------------

extern "C" void kernel_launch(void* const* d_in, const int* in_sizes, int n_in,
                              void* d_out, int out_size, void* d_ws, size_t ws_size,
                              hipStream_t stream) {
    const float* x    = (const float*)d_in[0];
    const int*   ei   = (const int*)d_in[1];
    const int*   batch= (const int*)d_in[2];
    const float* W1 = (const float*)d_in[3];
    const float* b1 = (const float*)d_in[4];
    const float* W2 = (const float*)d_in[5];
    const float* b2 = (const float*)d_in[6];
    const float* W3 = (const float*)d_in[7];
    const float* b3 = (const float*)d_in[8];
    const float* g1 = (const float*)d_in[9];
    const float* be1= (const float*)d_in[10];
    const float* rm1= (const float*)d_in[11];
    const float* rv1= (const float*)d_in[12];
    const float* g2 = (const float*)d_in[13];
    const float* be2= (const float*)d_in[14];
    const float* rm2= (const float*)d_in[15];
    const float* rv2= (const float*)d_in[16];
    const int* erow = ei;
    const int* ecol = ei + NE;

    char* ws = (char*)d_ws;
    size_t off = 0;
    auto alloc = [&](size_t bytes) -> void* {
        void* p = ws + off;
        off = (off + bytes + 255) & ~(size_t)255;
        return p;
    };
    int*    cnt     = (int*)alloc(NN * sizeof(int));
    int*    row_ptr = (int*)alloc((NN + 1) * sizeof(int));
    int*    cursor  = (int*)alloc(NN * sizeof(int));
    int*    csum    = (int*)alloc(64 * sizeof(int));
    int*    coff    = (int*)alloc(64 * sizeof(int));
    float*  dinv    = (float*)alloc(NN * sizeof(float));
    int*    esrc    = (int*)alloc(NEPAD * sizeof(int));
    __bf16* tbuf    = (__bf16*)alloc((size_t)NROWS * DIM * sizeof(__bf16));
    __bf16* hbuf    = (__bf16*)alloc((size_t)NN * DIM * sizeof(__bf16));
    float*  sc1     = (float*)alloc(DIM * sizeof(float));
    float*  sh1     = (float*)alloc(DIM * sizeof(float));
    float*  sc2     = (float*)alloc(DIM * sizeof(float));
    float*  sh2     = (float*)alloc(DIM * sizeof(float));

    hipMemsetAsync(cnt, 0, NN * sizeof(int), stream);
    hipMemsetAsync(d_out, 0, NG * DIM * sizeof(float), stream);

    bn_prep_kernel<<<1, 128, 0, stream>>>(b1, g1, be1, rm1, rv1,
                                          b2, g2, be2, rm2, rv2,
                                          sc1, sh1, sc2, sh2, tbuf);
    sentinel_kernel<<<1024, 256, 0, stream>>>((int4*)esrc);
    count_kernel<<<(NE / 4 + 255) / 256, 256, 0, stream>>>((const int4*)ecol, cnt);
    scan_chunk<<<NCHUNK, 256, 0, stream>>>(cnt, row_ptr, csum);
    scan_tail<<<1, 64, 0, stream>>>(csum, coff, row_ptr, NCHUNK);
    fixup_kernel<<<(NN + 255) / 256, 256, 0, stream>>>(row_ptr, coff, cnt, dinv, cursor);
    fill_kernel<<<NXCD * FILL_CHUNKS, 256, 0, stream>>>(erow, ecol, cursor, esrc);

    const unsigned* t32 = (const unsigned*)tbuf;
    const int nblk = (NN + 3) / 4;
    const int nblk_pool = (NN / RUN + 3) / 4;

    matmul_kernel<float><<<512, 256, 0, stream>>>(x, W1, dinv, tbuf);
    gather_bn_kernel<<<nblk, 256, 0, stream>>>(t32, row_ptr, esrc, dinv,
                                               sc1, sh1, hbuf);
    matmul_kernel<__bf16><<<512, 256, 0, stream>>>(hbuf, W2, dinv, tbuf);
    gather_bn_kernel<<<nblk, 256, 0, stream>>>(t32, row_ptr, esrc, dinv,
                                               sc2, sh2, hbuf);
    matmul_kernel<__bf16><<<512, 256, 0, stream>>>(hbuf, W3, dinv, tbuf);
    gather_pool_kernel<<<nblk_pool, 256, 0, stream>>>(t32, row_ptr, esrc, dinv,
                                                      b3, batch, (float*)d_out);
}